// Round 11
// baseline (1071.251 us; speedup 1.0000x reference)
//
#include <hip/hip_runtime.h>
#include <hip/hip_cooperative_groups.h>
#include <cmath>

namespace cg = cooperative_groups;

typedef __attribute__((ext_vector_type(8))) short bf16x8;
typedef __attribute__((ext_vector_type(8))) _Float16 f16x8;
typedef __attribute__((ext_vector_type(4))) float f32x4;

__device__ inline unsigned short f2bf_rne(float f) {
    unsigned int u = __float_as_uint(f);
    unsigned int r = (u + 0x7FFFu + ((u >> 16) & 1u)) >> 16;
    return (unsigned short)r;
}
__device__ inline float bf2f(unsigned short h) {
    return __uint_as_float(((unsigned int)h) << 16);
}

// fast tanh: (t-1)/(t+1), t = exp2(2x*log2e). ~7 VALU + 2 trans vs libm ~20.
__device__ inline float fast_tanh(float x) {
    float e = x * 2.8853900817779268f;            // 2*log2(e)
    e = fminf(fmaxf(e, -126.f), 126.f);
    float t = __builtin_amdgcn_exp2f(e);
    return (t - 1.0f) * __builtin_amdgcn_rcpf(t + 1.0f);
}

// ---------------- CSR build via two-level counting sort (R19/R20 form) ---------
// Packing (dlocal<<17|src) requires N <= 2^17.

constexpr int CB = 256;
constexpr int PREPB = 224;   // prep blocks appended after the CB hist blocks

__global__ __launch_bounds__(256) void k_prep_hist(
        const int* __restrict__ src, const int* __restrict__ dst,
        int* __restrict__ gH, int E, int K, int scanN, int chunk,
        const float* __restrict__ W0, const float* __restrict__ W1,
        const float* __restrict__ W2, const float* __restrict__ W3,
        unsigned short* __restrict__ h0, unsigned short* __restrict__ l0,
        unsigned short* __restrict__ h1, unsigned short* __restrict__ l1,
        unsigned short* __restrict__ h2, unsigned short* __restrict__ l2,
        unsigned short* __restrict__ h3, unsigned short* __restrict__ l3) {
    if (blockIdx.x < CB) {
        extern __shared__ int lds[];
        int* hd = lds; int* hs = lds + K;
        int cb = ((blockIdx.x & 7) * (CB >> 3)) + (blockIdx.x >> 3);   // XCD-contiguous chunk
        for (int i = threadIdx.x; i < 2 * K; i += 256) lds[i] = 0;
        __syncthreads();
        int lo = cb * chunk;
        int hi = lo + chunk; if (hi > E) hi = E;
        for (int i = lo + threadIdx.x; i < hi; i += 256) {
            atomicAdd(&hd[dst[i] >> 6], 1);
            atomicAdd(&hs[src[i] >> 6], 1);
        }
        __syncthreads();
        for (int k = threadIdx.x; k < K; k += 256) {
            gH[(size_t)k * CB + cb] = hd[k];
            gH[(size_t)(scanN + k * CB) + cb] = hs[k];
        }
    } else {
        int i = (blockIdx.x - CB) * 256 + threadIdx.x;
        const float* W; unsigned short* wh; unsigned short* wl; int N; int base; bool bf;
        if      (i < 16384) { W = W0; wh = h0; wl = l0; N = 128; base = i;         bf = true;  }
        else if (i < 32768) { W = W1; wh = h1; wl = l1; N = 128; base = i - 16384; bf = false; }
        else if (i < 49152) { W = W2; wh = h2; wl = l2; N = 128; base = i - 32768; bf = false; }
        else if (i < 57344) { W = W3; wh = h3; wl = l3; N = 64;  base = i - 49152; bf = false; }
        else return;
        int n = base >> 7, k = base & 127;
        float w = W[k * N + n];
        if (bf) {
            unsigned short hb = f2bf_rne(w);
            unsigned short lb = f2bf_rne(w - bf2f(hb));
            wh[base] = hb; wl[base] = lb;
        } else {
            union { _Float16 f; unsigned short u; } H, L;
            H.f = (_Float16)w;
            L.f = (_Float16)(w - (float)H.f);
            wh[base] = H.u; wl[base] = L.u;
        }
    }
}

__global__ __launch_bounds__(256) void k_bucket_scatter(const int* __restrict__ src,
                                                        const int* __restrict__ dst,
                                                        const int* __restrict__ gHS,
                                                        int* __restrict__ sortedAll,
                                                        int E, int K, int scanN, int chunk) {
    extern __shared__ int lds[];
    int* bd = lds; int* bs = lds + K;
    int cb = ((blockIdx.x & 7) * (CB >> 3)) + (blockIdx.x >> 3);   // XCD-contiguous chunk
    for (int k = threadIdx.x; k < K; k += 256) {
        bd[k] = gHS[(size_t)k * CB + cb];
        bs[k] = gHS[(size_t)(scanN + k * CB) + cb];
    }
    __syncthreads();
    int lo = cb * chunk;
    int hi = lo + chunk; if (hi > E) hi = E;
    for (int i = lo + threadIdx.x; i < hi; i += 256) {
        int d = dst[i], s = src[i];
        int pd = atomicAdd(&bd[d >> 6], 1);
        sortedAll[pd] = ((d & 63) << 17) | s;
        int ps = atomicAdd(&bs[s >> 6], 1);
        sortedAll[ps] = s;
    }
}

constexpr int FINE_CAP = 3072;

__global__ __launch_bounds__(256) void k_fine(const int* __restrict__ sortedAll,
                                              const int* __restrict__ gHS,
                                              int* __restrict__ rowptr,
                                              int* __restrict__ colidx,
                                              float* __restrict__ nsrc,
                                              float* __restrict__ ndst,
                                              int E, int K, int scanN, int N) {
    __shared__ int cnt[64], excl[64], rank[64];
    __shared__ int stage[FINE_CAP];
    int kb = blockIdx.x;
    bool isDst = kb < K;
    int k = isDst ? kb : kb - K;
    int bstart, bend;
    if (isDst) {
        bstart = gHS[(size_t)k * CB];
        bend = (k + 1 < K) ? gHS[(size_t)(k + 1) * CB] : E;
    } else {
        bstart = gHS[(size_t)(scanN + k * CB)];
        bend = (k + 1 < K) ? gHS[(size_t)(scanN + (k + 1) * CB)] : 2 * E;
    }
    int len = bend - bstart;
    bool useLds = isDst && (len <= FINE_CAP);
    if (threadIdx.x < 64) { cnt[threadIdx.x] = 0; rank[threadIdx.x] = 0; }
    if (useLds) {
        for (int i = threadIdx.x; i < len; i += 256)
            stage[i] = sortedAll[bstart + i];
    }
    __syncthreads();
    if (isDst) {
        if (useLds) {
            for (int i = threadIdx.x; i < len; i += 256)
                atomicAdd(&cnt[stage[i] >> 17], 1);
        } else {
            for (int i = bstart + threadIdx.x; i < bend; i += 256)
                atomicAdd(&cnt[sortedAll[i] >> 17], 1);
        }
    } else {
        for (int i = bstart + threadIdx.x; i < bend; i += 256)
            atomicAdd(&cnt[sortedAll[i] & 63], 1);
    }
    __syncthreads();
    if (isDst) {
        if (threadIdx.x == 0) {
            int r = 0;
            for (int j = 0; j < 64; j++) { excl[j] = r; r += cnt[j]; }
        }
        __syncthreads();
        int node0 = k << 6;
        if (threadIdx.x < 64) {
            int node = node0 + threadIdx.x;
            if (node < N) {
                rowptr[node] = bstart + excl[threadIdx.x];
                int c = cnt[threadIdx.x];
                ndst[node] = c > 0 ? rsqrtf((float)c) : 0.f;
            }
        }
        if (k == 0 && threadIdx.x == 0) rowptr[N] = E;
        if (useLds) {
            for (int i = threadIdx.x; i < len; i += 256) {
                int v = stage[i];
                int n = v >> 17;
                int r = atomicAdd(&rank[n], 1);
                colidx[bstart + excl[n] + r] = v & 0x1FFFF;
            }
        } else {
            for (int i = bstart + threadIdx.x; i < bend; i += 256) {
                int v = sortedAll[i];
                int n = v >> 17;
                int r = atomicAdd(&rank[n], 1);
                colidx[bstart + excl[n] + r] = v & 0x1FFFF;
            }
        }
    } else {
        int node = (k << 6) + threadIdx.x;
        if (threadIdx.x < 64 && node < N) {
            int c = cnt[threadIdx.x];
            nsrc[node] = c > 0 ? rsqrtf((float)c) : 0.f;
        }
    }
}

// ---------------- device-wide exclusive scan (tile = 2048, 2 kernels) ---------

constexpr int SCAN_TILE = 2048;

__global__ __launch_bounds__(256) void k_scan_partial(const int* __restrict__ deg,
                                                      int* __restrict__ tilesum, int n) {
    __shared__ int red[256];
    int base = blockIdx.x * SCAN_TILE;
    int s = 0;
    for (int i = threadIdx.x; i < SCAN_TILE; i += 256) {
        int idx = base + i;
        if (idx < n) s += deg[idx];
    }
    red[threadIdx.x] = s;
    __syncthreads();
    for (int off = 128; off > 0; off >>= 1) {
        if (threadIdx.x < off) red[threadIdx.x] += red[threadIdx.x + off];
        __syncthreads();
    }
    if (threadIdx.x == 0) tilesum[blockIdx.x] = red[0];
}

__global__ __launch_bounds__(256) void k_scan_final(const int* __restrict__ deg,
                                                    const int* __restrict__ tilesum,
                                                    int* __restrict__ outArr, int n) {
    __shared__ int red[256];
    __shared__ int sbase;
    int s0 = 0;
    for (int i = threadIdx.x; i < (int)blockIdx.x; i += 256) s0 += tilesum[i];
    red[threadIdx.x] = s0;
    __syncthreads();
    for (int off = 128; off > 0; off >>= 1) {
        if (threadIdx.x < off) red[threadIdx.x] += red[threadIdx.x + off];
        __syncthreads();
    }
    if (threadIdx.x == 0) sbase = red[0];
    __syncthreads();

    int base = blockIdx.x * SCAN_TILE;
    int lo = base + threadIdx.x * 8;
    int v[8]; int s = 0;
#pragma unroll
    for (int j = 0; j < 8; j++) {
        int idx = lo + j;
        v[j] = (idx < n) ? deg[idx] : 0;
        s += v[j];
    }
    red[threadIdx.x] = s;
    __syncthreads();
    for (int off = 1; off < 256; off <<= 1) {
        int x = red[threadIdx.x];
        int add = (threadIdx.x >= off) ? red[threadIdx.x - off] : 0;
        __syncthreads();
        red[threadIdx.x] = x + add;
        __syncthreads();
    }
    int excl = sbase + (threadIdx.x ? red[threadIdx.x - 1] : 0);
#pragma unroll
    for (int j = 0; j < 8; j++) {
        int idx = lo + j;
        if (idx < n) outArr[idx] = excl;
        excl += v[j];
    }
}

// ---------------- fused network: 8 phases, one cooperative dispatch (R21) -----
// R10 proved inter-dispatch overhead ~10-20us/boundary. The 8 compute
// dispatches (4 GEMM + 4 aggregate) become phases of ONE cooperative kernel
// separated by grid.sync(). All arithmetic is R10's code verbatim (same
// accumulation order -> bit-identical output); work distribution is
// grid-stride. LDS 36.9KB (GEMM staging) -> 4 blocks/CU; launch_bounds(256,4).

template <int DOUT, int SRC>
__device__ void gemm_dev(const float* __restrict__ xf, const _Float16* __restrict__ xq,
                         const unsigned short* __restrict__ wth,
                         const unsigned short* __restrict__ wtl,
                         const float* __restrict__ nsrc, _Float16* __restrict__ h,
                         int nrows, unsigned short* Bh, unsigned short* Bl, bool zrow) {
    constexpr int NT = DOUT / 16;
    constexpr int LDK = 72;
    int tid = threadIdx.x;
    int lane = tid & 63;
    int wv = tid >> 6;
    int quad = lane >> 4, l16 = lane & 15;

    if (zrow && blockIdx.x == 0 && tid < DOUT / 8) {
        f32x4 z = {0.f, 0.f, 0.f, 0.f};
        *(f32x4*)((char*)h + ((size_t)nrows * DOUT + tid * 8) * 2) = z;
    }

    int ntiles = (nrows + 63) >> 6;
    for (int tile = blockIdx.x; tile < ntiles; tile += gridDim.x) {
        int r0 = tile * 64 + wv * 16;
        int rowA = r0 + l16; if (rowA >= nrows) rowA = nrows - 1;

        f32x4 acc[NT];
#pragma unroll
        for (int nt = 0; nt < NT; nt++) acc[nt] = (f32x4){0.f, 0.f, 0.f, 0.f};

        for (int kh = 0; kh < 2; kh++) {
            __syncthreads();
            for (int i = tid; i < DOUT * 16; i += 256) {
                int n = i >> 4, kb = i & 15;
                int koff = kh * 64 + kb * 4;
                *(ushort4*)&Bh[n * LDK + kb * 4] = *(const ushort4*)&wth[n * 128 + koff];
                *(ushort4*)&Bl[n * LDK + kb * 4] = *(const ushort4*)&wtl[n * 128 + koff];
            }
            __syncthreads();

#pragma unroll
            for (int kq = 0; kq < 2; kq++) {
                int koA = kh * 64 + kq * 32 + quad * 8;
                int koB = kq * 32 + quad * 8;
                if (SRC == 0) {
                    const float* xp = &xf[(size_t)rowA * 128 + koA];
                    f32x4 x0 = *(const f32x4*)xp;
                    f32x4 x1 = *(const f32x4*)(xp + 4);
                    union { bf16x8 v; unsigned short u[8]; } H, L;
                    float xs[8] = {x0[0], x0[1], x0[2], x0[3], x1[0], x1[1], x1[2], x1[3]};
#pragma unroll
                    for (int j = 0; j < 8; j++) {
                        H.u[j] = f2bf_rne(xs[j]);
                        L.u[j] = f2bf_rne(xs[j] - bf2f(H.u[j]));
                    }
                    bf16x8 ah = H.v, al = L.v;
#pragma unroll
                    for (int nt = 0; nt < NT; nt++) {
                        int n = nt * 16 + l16;
                        bf16x8 bh = *(const bf16x8*)&Bh[n * LDK + koB];
                        bf16x8 bl = *(const bf16x8*)&Bl[n * LDK + koB];
                        acc[nt] = __builtin_amdgcn_mfma_f32_16x16x32_bf16(ah, bh, acc[nt], 0, 0, 0);
                        acc[nt] = __builtin_amdgcn_mfma_f32_16x16x32_bf16(ah, bl, acc[nt], 0, 0, 0);
                        acc[nt] = __builtin_amdgcn_mfma_f32_16x16x32_bf16(al, bh, acc[nt], 0, 0, 0);
                    }
                } else {
                    f16x8 aq = *(const f16x8*)&xq[(size_t)rowA * 128 + koA];
#pragma unroll
                    for (int nt = 0; nt < NT; nt++) {
                        int n = nt * 16 + l16;
                        f16x8 bh = *(const f16x8*)&Bh[n * LDK + koB];
                        f16x8 bl = *(const f16x8*)&Bl[n * LDK + koB];
                        acc[nt] = __builtin_amdgcn_mfma_f32_16x16x32_f16(aq, bh, acc[nt], 0, 0, 0);
                        acc[nt] = __builtin_amdgcn_mfma_f32_16x16x32_f16(aq, bl, acc[nt], 0, 0, 0);
                    }
                }
            }
        }

#pragma unroll
        for (int r = 0; r < 4; r++) {
            int row = r0 + quad * 4 + r;
            if (row < nrows) {
                float nm = nsrc[row];
#pragma unroll
                for (int nt = 0; nt < NT; nt++)
                    h[(size_t)row * DOUT + nt * 16 + l16] = (_Float16)(acc[nt][r] * nm);
            }
        }
        __syncthreads();
    }
}

template <int D, int MODE>
__device__ void agg_dev(const _Float16* __restrict__ h,
                        const int* __restrict__ rowptr,
                        const int* __restrict__ colidx,
                        const float* __restrict__ ndst,
                        const float* __restrict__ bias,
                        float* __restrict__ out,
                        _Float16* __restrict__ oq,
                        int n) {
    constexpr int FB = D / 8;
    constexpr int GN = 64 / FB;
    constexpr int EU = 4;
    int wid  = (blockIdx.x * 256 + threadIdx.x) >> 6;
    int lane = threadIdx.x & 63;
    int fb = lane & (FB - 1);
    int g  = lane / FB;
    int waveCount = gridDim.x * 4;

    for (int nbase = wid * GN; nbase < n; nbase += waveCount * GN) {
        int node = nbase + g;
        bool vn = node < n;
        int beg = vn ? rowptr[node] : 0;
        int end = vn ? rowptr[node + 1] : 0;
        int m = end - beg;

        int mmax = m;
#pragma unroll
        for (int off = FB; off < 64; off <<= 1) {
            int t = __shfl_xor(mmax, off);
            mmax = mmax > t ? mmax : t;
        }

        float acc[8];
#pragma unroll
        for (int k = 0; k < 8; k++) acc[k] = 0.f;

        int cv = 0;
        for (int j0 = 0; j0 < mmax; j0 += EU) {
            if ((j0 & (FB - 1)) == 0) {
                int idx = beg + j0 + fb;
                cv = __builtin_nontemporal_load(&colidx[idx < end ? idx : 0]);
            }
            int s[EU];
#pragma unroll
            for (int u = 0; u < EU; u++) {
                int j = j0 + u;
                int sv = __shfl(cv, g * FB + (j & (FB - 1)));
                s[u] = j < m ? sv : n;             // row n = zero row
            }
            f16x8 v[EU];
#pragma unroll
            for (int u = 0; u < EU; u++)
                v[u] = *(const f16x8*)&h[(size_t)s[u] * D + fb * 8];
#pragma unroll
            for (int u = 0; u < EU; u++) {
#pragma unroll
                for (int k = 0; k < 8; k++)
                    acc[k] += (float)v[u][k];
            }
        }

        if (vn) {
            float nd = ndst[node];
            float bv[8];
            *(float4*)&bv[0] = ((const float4*)bias)[fb * 2];
            *(float4*)&bv[4] = ((const float4*)bias)[fb * 2 + 1];
            float vv[8];
#pragma unroll
            for (int k = 0; k < 8; k++) vv[k] = acc[k] * nd + bv[k];
            if (MODE == 1) {
                f16x8 q;
#pragma unroll
                for (int k = 0; k < 8; k++)
                    q[k] = (_Float16)fast_tanh(vv[k]);
                *(f16x8*)&oq[(size_t)node * D + fb * 8] = q;
            } else {
                *(float4*)&out[(size_t)node * D + fb * 8] = *(float4*)&vv[0];
                *(float4*)&out[(size_t)node * D + fb * 8 + 4] = *(float4*)&vv[4];
            }
        }
    }
}

__global__ __launch_bounds__(256, 4) void k_net(
        const float* __restrict__ features, _Float16* __restrict__ xq,
        _Float16* __restrict__ bufH,
        const int* __restrict__ rowptr, const int* __restrict__ colidx,
        const float* __restrict__ nsrc, const float* __restrict__ ndst,
        const unsigned short* __restrict__ wt0h, const unsigned short* __restrict__ wt0l,
        const unsigned short* __restrict__ wt1h, const unsigned short* __restrict__ wt1l,
        const unsigned short* __restrict__ wt2h, const unsigned short* __restrict__ wt2l,
        const unsigned short* __restrict__ wt3h, const unsigned short* __restrict__ wt3l,
        const float* __restrict__ b0, const float* __restrict__ b1,
        const float* __restrict__ b2, const float* __restrict__ b3,
        float* __restrict__ out, int N) {
    __shared__ unsigned short Bh[128 * 72], Bl[128 * 72];
    cg::grid_group grid = cg::this_grid();

    gemm_dev<128, 0>(features, nullptr, wt0h, wt0l, nsrc, bufH, N, Bh, Bl, true);
    grid.sync();
    agg_dev<128, 1>(bufH, rowptr, colidx, ndst, b0, nullptr, xq, N);
    grid.sync();
    gemm_dev<128, 1>(nullptr, xq, wt1h, wt1l, nsrc, bufH, N, Bh, Bl, false);
    grid.sync();
    agg_dev<128, 1>(bufH, rowptr, colidx, ndst, b1, nullptr, xq, N);
    grid.sync();
    gemm_dev<128, 1>(nullptr, xq, wt2h, wt2l, nsrc, bufH, N, Bh, Bl, false);
    grid.sync();
    agg_dev<128, 1>(bufH, rowptr, colidx, ndst, b2, nullptr, xq, N);
    grid.sync();
    gemm_dev<64, 1>(nullptr, xq, wt3h, wt3l, nsrc, bufH, N, Bh, Bl, true);
    grid.sync();
    agg_dev<64, 0>(bufH, rowptr, colidx, ndst, b3, out, nullptr, N);
}

// ---------------- host ----------------

extern "C" void kernel_launch(void* const* d_in, const int* in_sizes, int n_in,
                              void* d_out, int out_size, void* d_ws, size_t ws_size,
                              hipStream_t stream) {
    const float* features = (const float*)d_in[0];
    const int* edges      = (const int*)d_in[1];
    const float* W0 = (const float*)d_in[2]; const float* b0 = (const float*)d_in[3];
    const float* W1 = (const float*)d_in[4]; const float* b1 = (const float*)d_in[5];
    const float* W2 = (const float*)d_in[6]; const float* b2 = (const float*)d_in[7];
    const float* W3 = (const float*)d_in[8]; const float* b3 = (const float*)d_in[9];
    float* out = (float*)d_out;

    const int N = in_sizes[0] / 128;
    const int E = in_sizes[1] / 2;
    const int* src = edges;
    const int* dst = edges + E;
    const int K = (N + 63) >> 6;
    const int chunk = (E + CB - 1) / CB;
    const int scanN = K * CB;
    const int n2 = 2 * scanN;
    const int numTiles = (n2 + SCAN_TILE - 1) / SCAN_TILE;
    const size_t dynLds = (size_t)2 * K * sizeof(int);

    char* p = (char*)d_ws;
    _Float16* bufH         = (_Float16*)p;       p += (size_t)N * 128 * 4;  // fp32-sized slot; row N = zero row
    _Float16* xq           = (_Float16*)p;       p += (size_t)(N + 1) * 128 * 2;
    char*     xspare       = p;                  p += (size_t)(N + 1) * 128 * 2;  // transient-sort spill
    int*   rowptr = (int*)p;   p += (((size_t)(N + 1) * 4 + 15) / 16) * 16;
    int*   colidx = (int*)p;   p += (size_t)E * 4;
    float* nsrc   = (float*)p; p += (size_t)N * 4;
    float* ndst   = (float*)p; p += (size_t)N * 4;
    int*   tilesum= (int*)p;   p += (((size_t)(numTiles + 1) * 4 + 15) / 16) * 16;
    unsigned short* wt0h = (unsigned short*)p; p += 16384 * 2;
    unsigned short* wt0l = (unsigned short*)p; p += 16384 * 2;
    unsigned short* wt1h = (unsigned short*)p; p += 16384 * 2;
    unsigned short* wt1l = (unsigned short*)p; p += 16384 * 2;
    unsigned short* wt2h = (unsigned short*)p; p += 16384 * 2;
    unsigned short* wt2l = (unsigned short*)p; p += 16384 * 2;
    unsigned short* wt3h = (unsigned short*)p; p += 8192 * 2;
    unsigned short* wt3l = (unsigned short*)p; p += 8192 * 2;

    // transient counting-sort buffers aliased into xq/xspare region
    char* q = (char*)xq;
    int* sortedAll = (int*)q; q += (size_t)2 * E * 4;
    int* gH        = (int*)q; q += (size_t)n2 * 4;
    int* gHS       = (int*)q; q += (size_t)(n2 + 1) * 4;
    (void)xspare;

    k_prep_hist<<<CB + PREPB, 256, dynLds, stream>>>(src, dst, gH, E, K, scanN, chunk,
                                                     W0, W1, W2, W3,
                                                     wt0h, wt0l, wt1h, wt1l,
                                                     wt2h, wt2l, wt3h, wt3l);
    k_scan_partial<<<numTiles, 256, 0, stream>>>(gH, tilesum, n2);
    k_scan_final<<<numTiles, 256, 0, stream>>>(gH, tilesum, gHS, n2);
    k_bucket_scatter<<<CB, 256, dynLds, stream>>>(src, dst, gHS, sortedAll, E, K, scanN, chunk);
    k_fine<<<2 * K, 256, 0, stream>>>(sortedAll, gHS, rowptr, colidx, nsrc, ndst, E, K, scanN, N);

    // cooperative fused network: grid sized to guaranteed co-residency
    static int bpc = -1;
    if (bpc < 0) {
        hipOccupancyMaxActiveBlocksPerMultiprocessor(&bpc, k_net, 256, 0);
        if (bpc < 1) bpc = 1;
    }
    int grid = bpc * 256;          // 256 CUs on MI355X
    if (grid > 2048) grid = 2048;

    void* args[] = {(void*)&features, (void*)&xq, (void*)&bufH,
                    (void*)&rowptr, (void*)&colidx, (void*)&nsrc, (void*)&ndst,
                    (void*)&wt0h, (void*)&wt0l, (void*)&wt1h, (void*)&wt1l,
                    (void*)&wt2h, (void*)&wt2l, (void*)&wt3h, (void*)&wt3l,
                    (void*)&b0, (void*)&b1, (void*)&b2, (void*)&b3,
                    (void*)&out, (void*)&N};
    hipLaunchCooperativeKernel((const void*)k_net, dim3(grid), dim3(256), args, 0, stream);
}

// Round 12
// 440.313 us; speedup vs baseline: 2.4329x; 2.4329x over previous
//
#include <hip/hip_runtime.h>
#include <cmath>

typedef __attribute__((ext_vector_type(8))) short bf16x8;
typedef __attribute__((ext_vector_type(8))) _Float16 f16x8;
typedef __attribute__((ext_vector_type(4))) float f32x4;

__device__ inline unsigned short f2bf_rne(float f) {
    unsigned int u = __float_as_uint(f);
    unsigned int r = (u + 0x7FFFu + ((u >> 16) & 1u)) >> 16;
    return (unsigned short)r;
}
__device__ inline float bf2f(unsigned short h) {
    return __uint_as_float(((unsigned int)h) << 16);
}

// fast tanh: (t-1)/(t+1), t = exp2(2x*log2e). ~7 VALU + 2 trans vs libm ~20.
__device__ inline float fast_tanh(float x) {
    float e = x * 2.8853900817779268f;            // 2*log2(e)
    e = fminf(fmaxf(e, -126.f), 126.f);
    float t = __builtin_amdgcn_exp2f(e);
    return (t - 1.0f) * __builtin_amdgcn_rcpf(t + 1.0f);
}

// ---------------- CSR build via two-level counting sort (R19/R20 form) ---------
// R21 (cooperative fusion) REVERTED: grid.sync() costs ~140us/sync on MI355X
// (cross-XCD spin), 10x worse than the dispatch boundary it replaces.
// Packing (dlocal<<17|src) requires N <= 2^17.

constexpr int CB = 256;
constexpr int PREPB = 224;   // prep blocks appended after the CB hist blocks

__global__ __launch_bounds__(256) void k_prep_hist(
        const int* __restrict__ src, const int* __restrict__ dst,
        int* __restrict__ gH, int E, int K, int scanN, int chunk,
        const float* __restrict__ W0, const float* __restrict__ W1,
        const float* __restrict__ W2, const float* __restrict__ W3,
        unsigned short* __restrict__ h0, unsigned short* __restrict__ l0,
        unsigned short* __restrict__ h1, unsigned short* __restrict__ l1,
        unsigned short* __restrict__ h2, unsigned short* __restrict__ l2,
        unsigned short* __restrict__ h3, unsigned short* __restrict__ l3) {
    if (blockIdx.x < CB) {
        extern __shared__ int lds[];
        int* hd = lds; int* hs = lds + K;
        int cb = ((blockIdx.x & 7) * (CB >> 3)) + (blockIdx.x >> 3);   // XCD-contiguous chunk
        for (int i = threadIdx.x; i < 2 * K; i += 256) lds[i] = 0;
        __syncthreads();
        int lo = cb * chunk;
        int hi = lo + chunk; if (hi > E) hi = E;
        for (int i = lo + threadIdx.x; i < hi; i += 256) {
            atomicAdd(&hd[dst[i] >> 6], 1);
            atomicAdd(&hs[src[i] >> 6], 1);
        }
        __syncthreads();
        for (int k = threadIdx.x; k < K; k += 256) {
            gH[(size_t)k * CB + cb] = hd[k];
            gH[(size_t)(scanN + k * CB) + cb] = hs[k];
        }
    } else {
        int i = (blockIdx.x - CB) * 256 + threadIdx.x;
        const float* W; unsigned short* wh; unsigned short* wl; int N; int base; bool bf;
        if      (i < 16384) { W = W0; wh = h0; wl = l0; N = 128; base = i;         bf = true;  }
        else if (i < 32768) { W = W1; wh = h1; wl = l1; N = 128; base = i - 16384; bf = false; }
        else if (i < 49152) { W = W2; wh = h2; wl = l2; N = 128; base = i - 32768; bf = false; }
        else if (i < 57344) { W = W3; wh = h3; wl = l3; N = 64;  base = i - 49152; bf = false; }
        else return;
        int n = base >> 7, k = base & 127;
        float w = W[k * N + n];
        if (bf) {
            unsigned short hb = f2bf_rne(w);
            unsigned short lb = f2bf_rne(w - bf2f(hb));
            wh[base] = hb; wl[base] = lb;
        } else {
            union { _Float16 f; unsigned short u; } H, L;
            H.f = (_Float16)w;
            L.f = (_Float16)(w - (float)H.f);
            wh[base] = H.u; wl[base] = L.u;
        }
    }
}

__global__ __launch_bounds__(256) void k_bucket_scatter(const int* __restrict__ src,
                                                        const int* __restrict__ dst,
                                                        const int* __restrict__ gHS,
                                                        int* __restrict__ sortedAll,
                                                        int E, int K, int scanN, int chunk) {
    extern __shared__ int lds[];
    int* bd = lds; int* bs = lds + K;
    int cb = ((blockIdx.x & 7) * (CB >> 3)) + (blockIdx.x >> 3);   // XCD-contiguous chunk
    for (int k = threadIdx.x; k < K; k += 256) {
        bd[k] = gHS[(size_t)k * CB + cb];
        bs[k] = gHS[(size_t)(scanN + k * CB) + cb];
    }
    __syncthreads();
    int lo = cb * chunk;
    int hi = lo + chunk; if (hi > E) hi = E;
    for (int i = lo + threadIdx.x; i < hi; i += 256) {
        int d = dst[i], s = src[i];
        int pd = atomicAdd(&bd[d >> 6], 1);
        sortedAll[pd] = ((d & 63) << 17) | s;
        int ps = atomicAdd(&bs[s >> 6], 1);
        sortedAll[ps] = s;
    }
}

constexpr int FINE_CAP = 3072;

__global__ __launch_bounds__(256) void k_fine(const int* __restrict__ sortedAll,
                                              const int* __restrict__ gHS,
                                              int* __restrict__ rowptr,
                                              int* __restrict__ colidx,
                                              float* __restrict__ nsrc,
                                              float* __restrict__ ndst,
                                              int E, int K, int scanN, int N) {
    __shared__ int cnt[64], excl[64], rank[64];
    __shared__ int stage[FINE_CAP];
    int kb = blockIdx.x;
    bool isDst = kb < K;
    int k = isDst ? kb : kb - K;
    int bstart, bend;
    if (isDst) {
        bstart = gHS[(size_t)k * CB];
        bend = (k + 1 < K) ? gHS[(size_t)(k + 1) * CB] : E;
    } else {
        bstart = gHS[(size_t)(scanN + k * CB)];
        bend = (k + 1 < K) ? gHS[(size_t)(scanN + (k + 1) * CB)] : 2 * E;
    }
    int len = bend - bstart;
    bool useLds = isDst && (len <= FINE_CAP);
    if (threadIdx.x < 64) { cnt[threadIdx.x] = 0; rank[threadIdx.x] = 0; }
    if (useLds) {
        for (int i = threadIdx.x; i < len; i += 256)
            stage[i] = sortedAll[bstart + i];
    }
    __syncthreads();
    if (isDst) {
        if (useLds) {
            for (int i = threadIdx.x; i < len; i += 256)
                atomicAdd(&cnt[stage[i] >> 17], 1);
        } else {
            for (int i = bstart + threadIdx.x; i < bend; i += 256)
                atomicAdd(&cnt[sortedAll[i] >> 17], 1);
        }
    } else {
        for (int i = bstart + threadIdx.x; i < bend; i += 256)
            atomicAdd(&cnt[sortedAll[i] & 63], 1);
    }
    __syncthreads();
    if (isDst) {
        if (threadIdx.x == 0) {
            int r = 0;
            for (int j = 0; j < 64; j++) { excl[j] = r; r += cnt[j]; }
        }
        __syncthreads();
        int node0 = k << 6;
        if (threadIdx.x < 64) {
            int node = node0 + threadIdx.x;
            if (node < N) {
                rowptr[node] = bstart + excl[threadIdx.x];
                int c = cnt[threadIdx.x];
                ndst[node] = c > 0 ? rsqrtf((float)c) : 0.f;
            }
        }
        if (k == 0 && threadIdx.x == 0) rowptr[N] = E;
        if (useLds) {
            for (int i = threadIdx.x; i < len; i += 256) {
                int v = stage[i];
                int n = v >> 17;
                int r = atomicAdd(&rank[n], 1);
                colidx[bstart + excl[n] + r] = v & 0x1FFFF;
            }
        } else {
            for (int i = bstart + threadIdx.x; i < bend; i += 256) {
                int v = sortedAll[i];
                int n = v >> 17;
                int r = atomicAdd(&rank[n], 1);
                colidx[bstart + excl[n] + r] = v & 0x1FFFF;
            }
        }
    } else {
        int node = (k << 6) + threadIdx.x;
        if (threadIdx.x < 64 && node < N) {
            int c = cnt[threadIdx.x];
            nsrc[node] = c > 0 ? rsqrtf((float)c) : 0.f;
        }
    }
}

// ---------------- device-wide exclusive scan (tile = 2048, 2 kernels) ---------

constexpr int SCAN_TILE = 2048;

__global__ __launch_bounds__(256) void k_scan_partial(const int* __restrict__ deg,
                                                      int* __restrict__ tilesum, int n) {
    __shared__ int red[256];
    int base = blockIdx.x * SCAN_TILE;
    int s = 0;
    for (int i = threadIdx.x; i < SCAN_TILE; i += 256) {
        int idx = base + i;
        if (idx < n) s += deg[idx];
    }
    red[threadIdx.x] = s;
    __syncthreads();
    for (int off = 128; off > 0; off >>= 1) {
        if (threadIdx.x < off) red[threadIdx.x] += red[threadIdx.x + off];
        __syncthreads();
    }
    if (threadIdx.x == 0) tilesum[blockIdx.x] = red[0];
}

__global__ __launch_bounds__(256) void k_scan_final(const int* __restrict__ deg,
                                                    const int* __restrict__ tilesum,
                                                    int* __restrict__ outArr, int n) {
    __shared__ int red[256];
    __shared__ int sbase;
    int s0 = 0;
    for (int i = threadIdx.x; i < (int)blockIdx.x; i += 256) s0 += tilesum[i];
    red[threadIdx.x] = s0;
    __syncthreads();
    for (int off = 128; off > 0; off >>= 1) {
        if (threadIdx.x < off) red[threadIdx.x] += red[threadIdx.x + off];
        __syncthreads();
    }
    if (threadIdx.x == 0) sbase = red[0];
    __syncthreads();

    int base = blockIdx.x * SCAN_TILE;
    int lo = base + threadIdx.x * 8;
    int v[8]; int s = 0;
#pragma unroll
    for (int j = 0; j < 8; j++) {
        int idx = lo + j;
        v[j] = (idx < n) ? deg[idx] : 0;
        s += v[j];
    }
    red[threadIdx.x] = s;
    __syncthreads();
    for (int off = 1; off < 256; off <<= 1) {
        int x = red[threadIdx.x];
        int add = (threadIdx.x >= off) ? red[threadIdx.x - off] : 0;
        __syncthreads();
        red[threadIdx.x] = x + add;
        __syncthreads();
    }
    int excl = sbase + (threadIdx.x ? red[threadIdx.x - 1] : 0);
#pragma unroll
    for (int j = 0; j < 8; j++) {
        int idx = lo + j;
        if (idx < n) outArr[idx] = excl;
        excl += v[j];
    }
}

// ---------------- GEMM: B in LDS, A direct from global (R22 split-h output) ----
// h is stored as TWO half-feature arrays h0/h1, each [(N+1) x 64] fp16 with
// contiguous 128B rows: features 0-63 -> h0, 64-127 -> h1 (DOUT=64 uses h0
// only). Pure store-address change; per-element math/order identical. Row N of
// each half = ZERO row (masked aggregate slots), written by every GEMM.

template <int DOUT, int SRC>
__global__ __launch_bounds__(256) void k_gemm_hyb(
        const float* __restrict__ xf, const _Float16* __restrict__ xq,
        const unsigned short* __restrict__ wth, const unsigned short* __restrict__ wtl,
        const float* __restrict__ nsrc, _Float16* __restrict__ h0arr,
        _Float16* __restrict__ h1arr, int nrows) {
    constexpr int NT = DOUT / 16;    // n-tiles per wave (8 or 4), wave owns 16 rows x DOUT
    constexpr int LDK = 72;          // 64 k-half + 8 pad (16B-aligned rows)
    __shared__ unsigned short Bh[DOUT * LDK], Bl[DOUT * LDK];

    int tid = threadIdx.x;
    int lane = tid & 63;
    int wv = tid >> 6;
    int quad = lane >> 4, l16 = lane & 15;
    int r0 = blockIdx.x * 64 + wv * 16;
    int rowA = r0 + l16; if (rowA >= nrows) rowA = nrows - 1;   // clamped load row

    // zero rows for the aggregate's masked edge slots
    if (blockIdx.x == 0 && tid < DOUT / 8) {
        f32x4 z = {0.f, 0.f, 0.f, 0.f};
        _Float16* hb = (tid < 8) ? h0arr : h1arr;
        *(f32x4*)((char*)hb + ((size_t)nrows * 64 + (tid & 7) * 8) * 2) = z;
    }

    f32x4 acc[NT];
#pragma unroll
    for (int nt = 0; nt < NT; nt++) acc[nt] = (f32x4){0.f, 0.f, 0.f, 0.f};

    for (int kh = 0; kh < 2; kh++) {
        if (kh) __syncthreads();
        // stage B half: DOUT n-rows x 64 k
        for (int i = tid; i < DOUT * 16; i += 256) {
            int n = i >> 4, kb = i & 15;
            int koff = kh * 64 + kb * 4;
            *(ushort4*)&Bh[n * LDK + kb * 4] = *(const ushort4*)&wth[n * 128 + koff];
            *(ushort4*)&Bl[n * LDK + kb * 4] = *(const ushort4*)&wtl[n * 128 + koff];
        }
        __syncthreads();

#pragma unroll
        for (int kq = 0; kq < 2; kq++) {
            int koA = kh * 64 + kq * 32 + quad * 8;   // global k offset for A
            int koB = kq * 32 + quad * 8;             // LDS offset within half
            if (SRC == 0) {
                const float* xp = &xf[(size_t)rowA * 128 + koA];
                f32x4 x0 = *(const f32x4*)xp;
                f32x4 x1 = *(const f32x4*)(xp + 4);
                union { bf16x8 v; unsigned short u[8]; } H, L;
                float xs[8] = {x0[0], x0[1], x0[2], x0[3], x1[0], x1[1], x1[2], x1[3]};
#pragma unroll
                for (int j = 0; j < 8; j++) {
                    H.u[j] = f2bf_rne(xs[j]);
                    L.u[j] = f2bf_rne(xs[j] - bf2f(H.u[j]));
                }
                bf16x8 ah = H.v, al = L.v;
#pragma unroll
                for (int nt = 0; nt < NT; nt++) {
                    int n = nt * 16 + l16;
                    bf16x8 bh = *(const bf16x8*)&Bh[n * LDK + koB];
                    bf16x8 bl = *(const bf16x8*)&Bl[n * LDK + koB];
                    acc[nt] = __builtin_amdgcn_mfma_f32_16x16x32_bf16(ah, bh, acc[nt], 0, 0, 0);
                    acc[nt] = __builtin_amdgcn_mfma_f32_16x16x32_bf16(ah, bl, acc[nt], 0, 0, 0);
                    acc[nt] = __builtin_amdgcn_mfma_f32_16x16x32_bf16(al, bh, acc[nt], 0, 0, 0);
                }
            } else {
                f16x8 aq = *(const f16x8*)&xq[(size_t)rowA * 128 + koA];
#pragma unroll
                for (int nt = 0; nt < NT; nt++) {
                    int n = nt * 16 + l16;
                    f16x8 bh = *(const f16x8*)&Bh[n * LDK + koB];
                    f16x8 bl = *(const f16x8*)&Bl[n * LDK + koB];
                    acc[nt] = __builtin_amdgcn_mfma_f32_16x16x32_f16(aq, bh, acc[nt], 0, 0, 0);
                    acc[nt] = __builtin_amdgcn_mfma_f32_16x16x32_f16(aq, bl, acc[nt], 0, 0, 0);
                }
            }
        }
    }

#pragma unroll
    for (int r = 0; r < 4; r++) {
        int row = r0 + quad * 4 + r;
        if (row < nrows) {
            float nm = nsrc[row];
#pragma unroll
            for (int nt = 0; nt < NT; nt++) {
                _Float16* hb = (DOUT == 128 && nt >= 4) ? h1arr : h0arr;
                int col = (DOUT == 128 ? (nt & 3) : nt) * 16 + l16;
                hb[(size_t)row * 64 + col] = (_Float16)(acc[nt][r] * nm);
            }
        }
    }
}

// ---------------- aggregation (R22): XCD-half feature partition ---------------
// half = blockIdx&1: under round-robin XCD dispatch (bid%8), even XCDs gather
// only h0 (12.8MB), odd only h1 — halves each L2's gather working set (6.4x ->
// 3.2x oversubscription). Per-feature accumulation order unchanged ->
// bit-identical. If XCD mapping differs, degenerates to mixed set (neutral).

__global__ __launch_bounds__(256) void k_agg128s(const _Float16* __restrict__ h0arr,
                                                 const _Float16* __restrict__ h1arr,
                                                 const int* __restrict__ rowptr,
                                                 const int* __restrict__ colidx,
                                                 const float* __restrict__ ndst,
                                                 const float* __restrict__ bias,
                                                 _Float16* __restrict__ oq,
                                                 int n) {
    constexpr int FB = 8;              // lanes per half-row (16B fp16 each)
    constexpr int GN = 8;              // nodes per wave
    constexpr int EU = 4;              // edges in flight per group
    int half = blockIdx.x & 1;
    const _Float16* h = half ? h1arr : h0arr;
    int bidh = blockIdx.x >> 1;
    int wid  = (bidh * 256 + threadIdx.x) >> 6;
    int lane = threadIdx.x & 63;
    int fb = lane & (FB - 1);
    int g  = lane / FB;
    int lbase = lane & ~(FB - 1);
    int waveCount = (gridDim.x >> 1) * 4;

    for (int nbase = wid * GN; nbase < n; nbase += waveCount * GN) {
        int node = nbase + g;
        bool vn = node < n;
        int beg = vn ? rowptr[node] : 0;
        int end = vn ? rowptr[node + 1] : 0;
        int m = end - beg;

        int mmax = m;
#pragma unroll
        for (int off = FB; off < 64; off <<= 1) {
            int t = __shfl_xor(mmax, off);
            mmax = mmax > t ? mmax : t;
        }

        float acc[8];
#pragma unroll
        for (int k = 0; k < 8; k++) acc[k] = 0.f;

        int cv = 0;
        for (int j0 = 0; j0 < mmax; j0 += EU) {
            if ((j0 & (FB - 1)) == 0) {
                int idx = beg + j0 + fb;
                cv = __builtin_nontemporal_load(&colidx[idx < end ? idx : 0]);
            }
            int s[EU];
#pragma unroll
            for (int u = 0; u < EU; u++) {
                int j = j0 + u;
                int sv = __shfl(cv, lbase + (j & (FB - 1)));
                s[u] = j < m ? sv : n;             // row n = zero row
            }
            f16x8 v[EU];
#pragma unroll
            for (int u = 0; u < EU; u++)
                v[u] = *(const f16x8*)&h[(size_t)s[u] * 64 + fb * 8];
#pragma unroll
            for (int u = 0; u < EU; u++) {
#pragma unroll
                for (int k = 0; k < 8; k++)
                    acc[k] += (float)v[u][k];
            }
        }

        if (vn) {
            float nd = ndst[node];
            float bv[8];
            *(float4*)&bv[0] = ((const float4*)bias)[half * 16 + fb * 2];
            *(float4*)&bv[4] = ((const float4*)bias)[half * 16 + fb * 2 + 1];
            f16x8 q;
#pragma unroll
            for (int k = 0; k < 8; k++)
                q[k] = (_Float16)fast_tanh(acc[k] * nd + bv[k]);
            *(f16x8*)&oq[(size_t)node * 128 + half * 64 + fb * 8] = q;
        }
    }
}

// final layer: D=64, fp32 out, reads h0 (same contiguous [(N+1)x64] layout)
__global__ __launch_bounds__(256) void k_agg64(const _Float16* __restrict__ h,
                                               const int* __restrict__ rowptr,
                                               const int* __restrict__ colidx,
                                               const float* __restrict__ ndst,
                                               const float* __restrict__ bias,
                                               float* __restrict__ out,
                                               int n) {
    constexpr int FB = 8;
    constexpr int GN = 8;
    constexpr int EU = 4;
    int wid  = (blockIdx.x * 256 + threadIdx.x) >> 6;
    int lane = threadIdx.x & 63;
    int fb = lane & (FB - 1);
    int g  = lane / FB;
    int lbase = lane & ~(FB - 1);
    int waveCount = gridDim.x * 4;

    for (int nbase = wid * GN; nbase < n; nbase += waveCount * GN) {
        int node = nbase + g;
        bool vn = node < n;
        int beg = vn ? rowptr[node] : 0;
        int end = vn ? rowptr[node + 1] : 0;
        int m = end - beg;

        int mmax = m;
#pragma unroll
        for (int off = FB; off < 64; off <<= 1) {
            int t = __shfl_xor(mmax, off);
            mmax = mmax > t ? mmax : t;
        }

        float acc[8];
#pragma unroll
        for (int k = 0; k < 8; k++) acc[k] = 0.f;

        int cv = 0;
        for (int j0 = 0; j0 < mmax; j0 += EU) {
            if ((j0 & (FB - 1)) == 0) {
                int idx = beg + j0 + fb;
                cv = __builtin_nontemporal_load(&colidx[idx < end ? idx : 0]);
            }
            int s[EU];
#pragma unroll
            for (int u = 0; u < EU; u++) {
                int j = j0 + u;
                int sv = __shfl(cv, lbase + (j & (FB - 1)));
                s[u] = j < m ? sv : n;             // row n = zero row
            }
            f16x8 v[EU];
#pragma unroll
            for (int u = 0; u < EU; u++)
                v[u] = *(const f16x8*)&h[(size_t)s[u] * 64 + fb * 8];
#pragma unroll
            for (int u = 0; u < EU; u++) {
#pragma unroll
                for (int k = 0; k < 8; k++)
                    acc[k] += (float)v[u][k];
            }
        }

        if (vn) {
            float nd = ndst[node];
            float bv[8];
            *(float4*)&bv[0] = ((const float4*)bias)[fb * 2];
            *(float4*)&bv[4] = ((const float4*)bias)[fb * 2 + 1];
            float vv[8];
#pragma unroll
            for (int k = 0; k < 8; k++) vv[k] = acc[k] * nd + bv[k];
            *(float4*)&out[(size_t)node * 64 + fb * 8] = *(float4*)&vv[0];
            *(float4*)&out[(size_t)node * 64 + fb * 8 + 4] = *(float4*)&vv[4];
        }
    }
}

// ---------------- host ----------------

extern "C" void kernel_launch(void* const* d_in, const int* in_sizes, int n_in,
                              void* d_out, int out_size, void* d_ws, size_t ws_size,
                              hipStream_t stream) {
    const float* features = (const float*)d_in[0];
    const int* edges      = (const int*)d_in[1];
    const float* W0 = (const float*)d_in[2]; const float* b0 = (const float*)d_in[3];
    const float* W1 = (const float*)d_in[4]; const float* b1 = (const float*)d_in[5];
    const float* W2 = (const float*)d_in[6]; const float* b2 = (const float*)d_in[7];
    const float* W3 = (const float*)d_in[8]; const float* b3 = (const float*)d_in[9];
    float* out = (float*)d_out;

    const int N = in_sizes[0] / 128;
    const int E = in_sizes[1] / 2;
    const int* src = edges;
    const int* dst = edges + E;
    const int K = (N + 63) >> 6;
    const int chunk = (E + CB - 1) / CB;
    const int scanN = K * CB;
    const int n2 = 2 * scanN;
    const int numTiles = (n2 + SCAN_TILE - 1) / SCAN_TILE;
    const size_t dynLds = (size_t)2 * K * sizeof(int);

    char* p = (char*)d_ws;
    _Float16* h0buf        = (_Float16*)p;       p += (size_t)(N + 1) * 64 * 2;
    _Float16* h1buf        = (_Float16*)p;       p += (size_t)(N + 1) * 64 * 2;
    _Float16* xq           = (_Float16*)p;       p += (size_t)(N + 1) * 128 * 2;
    char*     xspare       = p;                  p += (size_t)(N + 1) * 128 * 2;  // transient-sort spill
    int*   rowptr = (int*)p;   p += (((size_t)(N + 1) * 4 + 15) / 16) * 16;
    int*   colidx = (int*)p;   p += (size_t)E * 4;
    float* nsrc   = (float*)p; p += (size_t)N * 4;
    float* ndst   = (float*)p; p += (size_t)N * 4;
    int*   tilesum= (int*)p;   p += (((size_t)(numTiles + 1) * 4 + 15) / 16) * 16;
    unsigned short* wt0h = (unsigned short*)p; p += 16384 * 2;
    unsigned short* wt0l = (unsigned short*)p; p += 16384 * 2;
    unsigned short* wt1h = (unsigned short*)p; p += 16384 * 2;
    unsigned short* wt1l = (unsigned short*)p; p += 16384 * 2;
    unsigned short* wt2h = (unsigned short*)p; p += 16384 * 2;
    unsigned short* wt2l = (unsigned short*)p; p += 16384 * 2;
    unsigned short* wt3h = (unsigned short*)p; p += 8192 * 2;
    unsigned short* wt3l = (unsigned short*)p; p += 8192 * 2;

    // transient counting-sort buffers aliased into xq/xspare region
    char* q = (char*)xq;
    int* sortedAll = (int*)q; q += (size_t)2 * E * 4;
    int* gH        = (int*)q; q += (size_t)n2 * 4;
    int* gHS       = (int*)q; q += (size_t)(n2 + 1) * 4;
    (void)xspare;

    k_prep_hist<<<CB + PREPB, 256, dynLds, stream>>>(src, dst, gH, E, K, scanN, chunk,
                                                     W0, W1, W2, W3,
                                                     wt0h, wt0l, wt1h, wt1l,
                                                     wt2h, wt2l, wt3h, wt3l);
    k_scan_partial<<<numTiles, 256, 0, stream>>>(gH, tilesum, n2);
    k_scan_final<<<numTiles, 256, 0, stream>>>(gH, tilesum, gHS, n2);
    k_bucket_scatter<<<CB, 256, dynLds, stream>>>(src, dst, gHS, sortedAll, E, K, scanN, chunk);
    k_fine<<<2 * K, 256, 0, stream>>>(sortedAll, gHS, rowptr, colidx, nsrc, ndst, E, K, scanN, N);

    int gblk = (N + 63) / 64;
    int ablk128 = 2 * (((N + 7) / 8 + 3) / 4);   // 2 halves x blocks-per-half (4 waves x 8 nodes)
    int ablk64  = (N + 31) / 32;                 // 4 waves/block x 8 nodes/wave
    k_gemm_hyb<128, 0><<<gblk, 256, 0, stream>>>(features, nullptr, wt0h, wt0l, nsrc, h0buf, h1buf, N);
    k_agg128s<<<ablk128, 256, 0, stream>>>(h0buf, h1buf, rowptr, colidx, ndst, b0, xq, N);
    k_gemm_hyb<128, 1><<<gblk, 256, 0, stream>>>(nullptr, xq, wt1h, wt1l, nsrc, h0buf, h1buf, N);
    k_agg128s<<<ablk128, 256, 0, stream>>>(h0buf, h1buf, rowptr, colidx, ndst, b1, xq, N);
    k_gemm_hyb<128, 1><<<gblk, 256, 0, stream>>>(nullptr, xq, wt2h, wt2l, nsrc, h0buf, h1buf, N);
    k_agg128s<<<ablk128, 256, 0, stream>>>(h0buf, h1buf, rowptr, colidx, ndst, b2, xq, N);
    k_gemm_hyb<64, 1><<<gblk, 256, 0, stream>>>(nullptr, xq, wt3h, wt3l, nsrc, h0buf, h1buf, N);
    k_agg64<<<ablk64, 256, 0, stream>>>(h0buf, rowptr, colidx, ndst, b3, out, N);
}